// Round 10
// baseline (1855.592 us; speedup 1.0000x reference)
//
#include <hip/hip_runtime.h>

#define H 64
#define NN 100000
#define NE 1000000
#define EPS 1e-6f

// ROUND 16: dbuf prefetch AND high occupancy. r14 (serial loads, 29.7KB,
// 5 blk/CU) = 399us; r15 (dbuf prefetch, 41KB, 3 blk/CU) = 414us -- the
// prefetch gain and the occupancy loss canceled. Occupancy is the hiding
// mechanism for barrier drains, LDS bytes buy it. Fix: K=8 HALF-phases:
// aT[2][8x256] (16KB) + Wb[2][8x64] (4KB) + rBlk (1KB) = 21.5KB -> 7
// blocks/CU (VGPR ~68 -> 7 waves/SIMD OK). 24 barriers (r14 count) but
// now with prefetch AND ~7 resident blocks to hide each drain. Total LDS
// bytes, FMA count, r12 row-atomic epilogue, r14 cache policy: unchanged.

typedef __attribute__((ext_vector_type(4))) float f32v4;

__global__ __launch_bounds__(256, 3) void edge_hp(
    const float* __restrict__ nodes, const float* __restrict__ edges,
    const int* __restrict__ senders, const int* __restrict__ receivers,
    const float* __restrict__ We, const float* __restrict__ be,
    const float* __restrict__ ln_s, const float* __restrict__ ln_b,
    float* recv_agg, float* __restrict__ edges_out) {
  __shared__ __align__(16) float aT[2][8 * 256];  // 16 KB dbuf: [k][edge];
                                                  // reused as wave slices
  __shared__ __align__(16) float Wb[2][8 * 64];   // 4 KB dbuf: W chunk
  __shared__ int rBlk[256];                       // 1 KB
  const int tid = threadIdx.x;
  const int e0 = blockIdx.x * 256;
  const int myE = e0 + tid;
  const int eC = myE < NE ? myE : NE - 1;  // clamped: loads only
  const int sIdx = senders[eC];
  const int rIdx = receivers[eC];
  rBlk[tid] = rIdx;

  float acc[8][8];
#pragma unroll
  for (int j = 0; j < 8; ++j)
#pragma unroll
    for (int i = 0; i < 8; ++i) acc[j][i] = 0.0f;

  const int te = (tid >> 3) * 8;  // 32 groups x 8 edges
  const int tc = (tid & 7) * 8;   // 8 groups x 8 cols

  // Half-phase hp (K=8, 24 total): A = 32B of this thread's own row
  // (hp<8 edges, hp<16 sender, else receiver; cacheable -- the residual
  // re-read depends on L2/L3 hits) + W rows [8hp,8hp+8) (2 floats/thread).
#define LOAD_AW(HP)                                                            \
  {                                                                            \
    const int h_ = (HP);                                                       \
    const float* s_;                                                           \
    if (h_ < 8)       s_ = edges + (size_t)eC * H + h_ * 8;                    \
    else if (h_ < 16) s_ = nodes + (size_t)sIdx * H + (h_ - 8) * 8;            \
    else              s_ = nodes + (size_t)rIdx * H + (h_ - 16) * 8;           \
    v0 = *(const f32v4*)(s_ + 0);                                              \
    v1 = *(const f32v4*)(s_ + 4);                                              \
    wv2 = *(const float2*)(We + (size_t)h_ * (8 * 64) + tid * 2);              \
  }

  // transpose write: aT[B][k][e=tid]; bank = tid%32: conflict-free
#define WRITE_BUF(B)                                                           \
  {                                                                            \
    aT[B][0 * 256 + tid] = v0.x; aT[B][1 * 256 + tid] = v0.y;                  \
    aT[B][2 * 256 + tid] = v0.z; aT[B][3 * 256 + tid] = v0.w;                  \
    aT[B][4 * 256 + tid] = v1.x; aT[B][5 * 256 + tid] = v1.y;                  \
    aT[B][6 * 256 + tid] = v1.z; aT[B][7 * 256 + tid] = v1.w;                  \
    *(float2*)(&Wb[B][tid * 2]) = wv2;                                         \
  }

#define COMPUTE(B)                                                             \
  {                                                                            \
    const float* __restrict__ ap = aT[B];                                      \
    const float* __restrict__ wp = Wb[B];                                      \
    _Pragma("unroll")                                                          \
    for (int kk = 0; kk < 8; ++kk) {                                           \
      f32v4 a0 = *(const f32v4*)(&ap[kk * 256 + te + 0]);                      \
      f32v4 a1 = *(const f32v4*)(&ap[kk * 256 + te + 4]);                      \
      f32v4 w0 = *(const f32v4*)(&wp[kk * 64 + tc + 0]);                       \
      f32v4 w1 = *(const f32v4*)(&wp[kk * 64 + tc + 4]);                       \
      const float av[8] = {a0.x, a0.y, a0.z, a0.w, a1.x, a1.y, a1.z, a1.w};    \
      const float wv[8] = {w0.x, w0.y, w0.z, w0.w, w1.x, w1.y, w1.z, w1.w};    \
      _Pragma("unroll")                                                        \
      for (int j = 0; j < 8; ++j)                                              \
        _Pragma("unroll")                                                      \
        for (int i = 0; i < 8; ++i)                                            \
          acc[j][i] = fmaf(av[j], wv[i], acc[j][i]);                           \
    }                                                                          \
  }

  f32v4 v0, v1;
  float2 wv2;
  // prologue: stage half-phase 0 into buf 0 (latency exposed once)
  LOAD_AW(0);
  WRITE_BUF(0);
  __syncthreads();

  // steady state: loads(hp+1) fly under compute(hp); write the OTHER
  // buffer (no reader until after the barrier); one barrier per half-phase.
#pragma unroll 2
  for (int hp = 0; hp < 24; ++hp) {
    const int cur = hp & 1, nxt = cur ^ 1;
    if (hp < 23) LOAD_AW(hp + 1);
    COMPUTE(cur);
    if (hp < 23) WRITE_BUF(nxt);
    __syncthreads();
  }
#undef LOAD_AW
#undef WRITE_BUF
#undef COMPUTE
  // after the final barrier all compute is done: aT reusable as slices

  // ---- epilogue part 1: bias -> LN -> store; acc := n (pre-residual) ----
  const f32v4 be0 = *(const f32v4*)(be + tc);
  const f32v4 be1 = *(const f32v4*)(be + tc + 4);
  const f32v4 se0 = *(const f32v4*)(ln_s + tc);
  const f32v4 se1 = *(const f32v4*)(ln_s + tc + 4);
  const f32v4 bi0 = *(const f32v4*)(ln_b + tc);
  const f32v4 bi1 = *(const f32v4*)(ln_b + tc + 4);
  const float bb[8] = {be0.x, be0.y, be0.z, be0.w, be1.x, be1.y, be1.z, be1.w};
  const float ss[8] = {se0.x, se0.y, se0.z, se0.w, se1.x, se1.y, se1.z, se1.w};
  const float ll[8] = {bi0.x, bi0.y, bi0.z, bi0.w, bi1.x, bi1.y, bi1.z, bi1.w};

#pragma unroll
  for (int j = 0; j < 8; ++j) {
    const int row = te + j;
    const int ge = e0 + row;
    const bool valid = ge < NE;
    const int geC = valid ? ge : NE - 1;
    // residual re-read: cacheable (L2/L3-hot from the GEMM phase reads)
    const f32v4 r0 = *(const f32v4*)(edges + (size_t)geC * H + tc);
    const f32v4 r1 = *(const f32v4*)(edges + (size_t)geC * H + tc + 4);
    const float rr[8] = {r0.x, r0.y, r0.z, r0.w, r1.x, r1.y, r1.z, r1.w};
    float t8[8];
#pragma unroll
    for (int i = 0; i < 8; ++i) {
      const float n = acc[j][i] + bb[i];
      acc[j][i] = n;  // keep pre-residual value for the atomic pass
      t8[i] = n + rr[i];
    }
    float s1 = 0.f, s2 = 0.f;
#pragma unroll
    for (int i = 0; i < 8; ++i) { s1 += t8[i]; s2 = fmaf(t8[i], t8[i], s2); }
    // row held by the 8 lanes sharing te: xor 1,2,4
    s1 += __shfl_xor(s1, 1, 64); s2 += __shfl_xor(s2, 1, 64);
    s1 += __shfl_xor(s1, 2, 64); s2 += __shfl_xor(s2, 2, 64);
    s1 += __shfl_xor(s1, 4, 64); s2 += __shfl_xor(s2, 4, 64);
    const float mean = s1 * (1.0f / 64.0f);
    const float var = s2 * (1.0f / 64.0f) - mean * mean;
    const float rstd = rsqrtf(var + EPS);
    if (valid) {
      f32v4 o0, o1;
      o0.x = (t8[0] - mean) * rstd * ss[0] + ll[0];
      o0.y = (t8[1] - mean) * rstd * ss[1] + ll[1];
      o0.z = (t8[2] - mean) * rstd * ss[2] + ll[2];
      o0.w = (t8[3] - mean) * rstd * ss[3] + ll[3];
      o1.x = (t8[4] - mean) * rstd * ss[4] + ll[4];
      o1.y = (t8[5] - mean) * rstd * ss[5] + ll[5];
      o1.z = (t8[6] - mean) * rstd * ss[6] + ll[6];
      o1.w = (t8[7] - mean) * rstd * ss[7] + ll[7];
      float* po = edges_out + (size_t)ge * H + tc;
      __builtin_nontemporal_store(o0, (f32v4*)(po + 0));  // never re-read
      __builtin_nontemporal_store(o1, (f32v4*)(po + 4));
    }
  }

  // ---- epilogue part 2: per-wave transpose -> row-contiguous atomics ----
  // Wave wv owns block rows [64wv,64wv+64) + a private 4KB slice of aT
  // (aT total is 16KB = 4 x 4KB): no cross-wave hazard, no barriers. One
  // atomic instr per edge covers the full 256B recv row (8 sectors, 1x
  // amplification) -- the r12 win.
  const int wv = tid >> 6;
  const int l = tid & 63;
  float* slice = &aT[0][0] + wv * 1024;  // 16 rows x 64 cols
#pragma unroll 1
  for (int s = 0; s < 4; ++s) {
    if ((l >> 4) == s) {
      const int rb = ((l >> 3) & 1) * 8;  // slice-row base for this lane
#pragma unroll
      for (int j = 0; j < 8; ++j) {
        f32v4 x0, x1;
        x0.x = acc[j][0]; x0.y = acc[j][1]; x0.z = acc[j][2]; x0.w = acc[j][3];
        x1.x = acc[j][4]; x1.y = acc[j][5]; x1.z = acc[j][6]; x1.w = acc[j][7];
        *(f32v4*)(&slice[(rb + j) * 64 + tc + 0]) = x0;
        *(f32v4*)(&slice[(rb + j) * 64 + tc + 4]) = x1;
      }
    }
#pragma unroll 4
    for (int e = 0; e < 16; ++e) {
      const int row = wv * 64 + s * 16 + e;
      const int ge = e0 + row;
      if (ge < NE) {  // uniform per instruction
        const float v = slice[e * 64 + l];  // stride-1 across lanes: free
        atomicAdd(recv_agg + (size_t)rBlk[row] * H + l, v);
      }
    }
  }
}

// ---- node kernel: unchanged (not the bottleneck, ~37 µs).
__global__ __launch_bounds__(256, 3) void node_tiled(
    const float* __restrict__ nodes, const float* recv_agg,
    const float* __restrict__ Wn, const float* __restrict__ bn,
    const float* __restrict__ ln_s, const float* __restrict__ ln_b,
    float* nodes_out) {
  __shared__ __align__(16) float aT[64 * 64];    // 16 KB: [k-k0][n]
  __shared__ __align__(16) float Wb[128 * 64];   // 32 KB
  const int tid = threadIdx.x;
  const int n0 = blockIdx.x * 64;

#pragma unroll
  for (int t = 0; t < 8; ++t) {
    int ci = t * 256 + tid;
    *(float4*)(&Wb[ci * 4]) = *(const float4*)(Wn + ci * 4);
  }

  float acc[4][4];
#pragma unroll
  for (int j = 0; j < 4; ++j)
#pragma unroll
    for (int i = 0; i < 4; ++i) acc[j][i] = 0.0f;

  const int te = (tid >> 4) * 4;
  const int tc = (tid & 15) * 4;

#pragma unroll
  for (int p = 0; p < 2; ++p) {
    const int k0 = 64 * p;
#pragma unroll
    for (int t = 0; t < 4; ++t) {
      int ci = t * 256 + tid;                     // 1024 float4
      int n = ci & 63, kq = ci >> 6;              // kq 0..15
      int kg = k0 + kq * 4;
      int gn = n0 + n;
      int gnc = gn < NN ? gn : NN - 1;
      const float* src = (kg < 64) ? (nodes + (size_t)gnc * H + kg)
                                   : (recv_agg + (size_t)gnc * H + (kg - 64));
      float4 v = *(const float4*)src;
      aT[(kq * 4 + 0) * 64 + n] = v.x;
      aT[(kq * 4 + 1) * 64 + n] = v.y;
      aT[(kq * 4 + 2) * 64 + n] = v.z;
      aT[(kq * 4 + 3) * 64 + n] = v.w;
    }
    __syncthreads();
#pragma unroll 4
    for (int kk = 0; kk < 64; ++kk) {
      float4 a4 = *(const float4*)(&aT[kk * 64 + te]);
      float4 w4 = *(const float4*)(&Wb[(k0 + kk) * 64 + tc]);
      float av[4] = {a4.x, a4.y, a4.z, a4.w};
      float wv[4] = {w4.x, w4.y, w4.z, w4.w};
#pragma unroll
      for (int j = 0; j < 4; ++j)
#pragma unroll
        for (int i = 0; i < 4; ++i) acc[j][i] += av[j] * wv[i];
    }
    __syncthreads();
  }

  const float4 bev = *(const float4*)(bn + tc);
  const float4 sev = *(const float4*)(ln_s + tc);
  const float4 biv = *(const float4*)(ln_b + tc);
#pragma unroll
  for (int j = 0; j < 4; ++j) {
    int gn = n0 + te + j;
    bool valid = gn < NN;
    float4 nv;
    if (valid) nv = *(const float4*)(nodes + (size_t)gn * H + tc);
    else { nv.x = nv.y = nv.z = nv.w = 0.0f; }
    float t0 = acc[j][0] + bev.x + nv.x;
    float t1 = acc[j][1] + bev.y + nv.y;
    float t2 = acc[j][2] + bev.z + nv.z;
    float t3 = acc[j][3] + bev.w + nv.w;
    float s1 = t0 + t1 + t2 + t3;
    float s2 = t0 * t0 + t1 * t1 + t2 * t2 + t3 * t3;
    s1 += __shfl_xor(s1, 1, 64); s2 += __shfl_xor(s2, 1, 64);
    s1 += __shfl_xor(s1, 2, 64); s2 += __shfl_xor(s2, 2, 64);
    s1 += __shfl_xor(s1, 4, 64); s2 += __shfl_xor(s2, 4, 64);
    s1 += __shfl_xor(s1, 8, 64); s2 += __shfl_xor(s2, 8, 64);
    float mean = s1 * (1.0f / 64.0f);
    float var = s2 * (1.0f / 64.0f) - mean * mean;
    float rstd = rsqrtf(var + EPS);
    if (valid) {
      float4 o;
      o.x = (t0 - mean) * rstd * sev.x + biv.x;
      o.y = (t1 - mean) * rstd * sev.y + biv.y;
      o.z = (t2 - mean) * rstd * sev.z + biv.z;
      o.w = (t3 - mean) * rstd * sev.w + biv.w;
      *(float4*)(nodes_out + (size_t)gn * H + tc) = o;
    }
  }
}

extern "C" void kernel_launch(void* const* d_in, const int* in_sizes, int n_in,
                              void* d_out, int out_size, void* d_ws, size_t ws_size,
                              hipStream_t stream) {
  const float* nodes      = (const float*)d_in[0];
  const float* edges      = (const float*)d_in[1];
  const int*   senders    = (const int*)d_in[2];
  const int*   receivers  = (const int*)d_in[3];
  const float* We         = (const float*)d_in[4];
  const float* be         = (const float*)d_in[5];
  const float* Wn         = (const float*)d_in[6];
  const float* bn         = (const float*)d_in[7];
  const float* ln_n_scale = (const float*)d_in[8];
  const float* ln_n_bias  = (const float*)d_in[9];
  const float* ln_e_scale = (const float*)d_in[10];
  const float* ln_e_bias  = (const float*)d_in[11];

  float* out = (float*)d_out;
  float* nodes_out = out;                       // [NN,64]; doubles as recv_agg
  float* edges_out = out + (size_t)NN * H;      // [NE,64]

  (void)hipMemsetAsync(nodes_out, 0, (size_t)NN * H * sizeof(float), stream);
  edge_hp<<<(NE + 255) / 256, 256, 0, stream>>>(
      nodes, edges, senders, receivers, We, be, ln_e_scale, ln_e_bias,
      nodes_out, edges_out);
  node_tiled<<<(NN + 63) / 64, 256, 0, stream>>>(nodes, nodes_out, Wn, bn,
                                                 ln_n_scale, ln_n_bias, nodes_out);
}

// Round 11
// 454.545 us; speedup vs baseline: 4.0823x; 4.0823x over previous
//
#include <hip/hip_runtime.h>

#define H 64
#define NN 100000
#define NE 1000000
#define EPS 1e-6f

// ROUND 17: r14 structure + minimal-LDS W staging. r16 lesson: per-thread
// global gather granule must stay 64B (32B pieces -> ~4x HBM amplification
// via 128B fetch granule + L2 thrash: FETCH 3.3GB, WRITE 5GB). r14 lesson
// chain: occupancy (blocks/CU) is the hiding mechanism for barrier drains;
// LDS bytes buy it. Change vs r14 (399us, 5 blk/CU @ 29.7KB): stage W per
// K=16 PHASE (4KB single buffer) instead of per-quarter (12KB). W is
// linear + L2-resident (48KB total, all blocks share) so its 16B/thread
// granule is safe (r15 did the same W pattern cleanly). LDS 16+4+1 = 21KB
// -> 7 blocks/CU (VGPR limit at r14's 60 regs is 8 waves/SIMD; LDS binds).
// A-loads stay 64B serial-staged with 2 barriers/phase exactly as r14.
// Epilogue (LN -> NT stores -> row-contiguous atomics LAST) unchanged.

typedef __attribute__((ext_vector_type(4))) float f32v4;

__global__ __launch_bounds__(256, 3) void edge_p(
    const float* __restrict__ nodes, const float* __restrict__ edges,
    const int* __restrict__ senders, const int* __restrict__ receivers,
    const float* __restrict__ We, const float* __restrict__ be,
    const float* __restrict__ ln_s, const float* __restrict__ ln_b,
    float* recv_agg, float* __restrict__ edges_out) {
  __shared__ __align__(16) float aT[16 * 256];  // 16 KB: [k][edge] per phase;
                                                // reused as 4x4KB wave slices
  __shared__ __align__(16) float Wb[16 * 64];   // 4 KB: current W phase-chunk
  __shared__ int rBlk[256];                     // 1 KB
  const int tid = threadIdx.x;
  const int e0 = blockIdx.x * 256;
  const int myE = e0 + tid;
  const int eC = myE < NE ? myE : NE - 1;  // clamped: loads only
  const int sIdx = senders[eC];
  const int rIdx = receivers[eC];
  rBlk[tid] = rIdx;

  float acc[8][8];
#pragma unroll
  for (int j = 0; j < 8; ++j)
#pragma unroll
    for (int i = 0; i < 8; ++i) acc[j][i] = 0.0f;

  const int te = (tid >> 3) * 8;  // 32 groups x 8 edges
  const int tc = (tid & 7) * 8;   // 8 groups x 8 cols

  // Phase p (K=16, 12 total): A = one full 64B line of this thread's own
  // row (p<4 edges, p<8 sender, else receiver; cacheable -- the residual
  // re-read depends on L2/L3 hits). W = rows [16p,16p+16): 4 floats/thread
  // (16B granule OK: We is linear + L2-resident across all blocks).
#define LOAD_AW(P)                                                             \
  {                                                                            \
    const int p_ = (P);                                                        \
    const float* s_;                                                           \
    if (p_ < 4)      s_ = edges + (size_t)eC * H + p_ * 16;                    \
    else if (p_ < 8) s_ = nodes + (size_t)sIdx * H + (p_ - 4) * 16;            \
    else             s_ = nodes + (size_t)rIdx * H + (p_ - 8) * 16;            \
    v0 = *(const f32v4*)(s_ + 0);  v1 = *(const f32v4*)(s_ + 4);               \
    v2 = *(const f32v4*)(s_ + 8);  v3 = *(const f32v4*)(s_ + 12);              \
    wv4 = *(const f32v4*)(We + (size_t)p_ * (16 * 64) + tid * 4);              \
  }

  // transpose write: aT[k][e=tid]; bank = tid%32: conflict-free
#define WRITE_BUF()                                                            \
  {                                                                            \
    aT[0 * 256 + tid] = v0.x;  aT[1 * 256 + tid] = v0.y;                       \
    aT[2 * 256 + tid] = v0.z;  aT[3 * 256 + tid] = v0.w;                       \
    aT[4 * 256 + tid] = v1.x;  aT[5 * 256 + tid] = v1.y;                       \
    aT[6 * 256 + tid] = v1.z;  aT[7 * 256 + tid] = v1.w;                       \
    aT[8 * 256 + tid] = v2.x;  aT[9 * 256 + tid] = v2.y;                       \
    aT[10 * 256 + tid] = v2.z; aT[11 * 256 + tid] = v2.w;                      \
    aT[12 * 256 + tid] = v3.x; aT[13 * 256 + tid] = v3.y;                      \
    aT[14 * 256 + tid] = v3.z; aT[15 * 256 + tid] = v3.w;                      \
    *(f32v4*)(&Wb[tid * 4]) = wv4;                                             \
  }

#define COMPUTE()                                                              \
  {                                                                            \
    _Pragma("unroll 4")                                                        \
    for (int kk = 0; kk < 16; ++kk) {                                          \
      f32v4 a0 = *(const f32v4*)(&aT[kk * 256 + te + 0]);                      \
      f32v4 a1 = *(const f32v4*)(&aT[kk * 256 + te + 4]);                      \
      f32v4 w0 = *(const f32v4*)(&Wb[kk * 64 + tc + 0]);                       \
      f32v4 w1 = *(const f32v4*)(&Wb[kk * 64 + tc + 4]);                       \
      const float av[8] = {a0.x, a0.y, a0.z, a0.w, a1.x, a1.y, a1.z, a1.w};    \
      const float wv[8] = {w0.x, w0.y, w0.z, w0.w, w1.x, w1.y, w1.z, w1.w};    \
      _Pragma("unroll")                                                        \
      for (int j = 0; j < 8; ++j)                                              \
        _Pragma("unroll")                                                      \
        for (int i = 0; i < 8; ++i)                                            \
          acc[j][i] = fmaf(av[j], wv[i], acc[j][i]);                           \
    }                                                                          \
  }

  f32v4 v0, v1, v2, v3, wv4;
  // 12 phases; loads for phase p issued BEFORE barrier #1 so they fly
  // under the previous phase's compute (r14 behavior).
#pragma unroll 1
  for (int p = 0; p < 12; ++p) {
    LOAD_AW(p);
    __syncthreads();  // previous compute done reading aT + Wb
    WRITE_BUF();
    __syncthreads();
    COMPUTE();
  }
#undef LOAD_AW
#undef WRITE_BUF
#undef COMPUTE
  __syncthreads();  // all waves done reading aT: safe to reuse as slices

  // ---- epilogue part 1: bias -> LN -> store; acc := n (pre-residual) ----
  const f32v4 be0 = *(const f32v4*)(be + tc);
  const f32v4 be1 = *(const f32v4*)(be + tc + 4);
  const f32v4 se0 = *(const f32v4*)(ln_s + tc);
  const f32v4 se1 = *(const f32v4*)(ln_s + tc + 4);
  const f32v4 bi0 = *(const f32v4*)(ln_b + tc);
  const f32v4 bi1 = *(const f32v4*)(ln_b + tc + 4);
  const float bb[8] = {be0.x, be0.y, be0.z, be0.w, be1.x, be1.y, be1.z, be1.w};
  const float ss[8] = {se0.x, se0.y, se0.z, se0.w, se1.x, se1.y, se1.z, se1.w};
  const float ll[8] = {bi0.x, bi0.y, bi0.z, bi0.w, bi1.x, bi1.y, bi1.z, bi1.w};

#pragma unroll
  for (int j = 0; j < 8; ++j) {
    const int row = te + j;
    const int ge = e0 + row;
    const bool valid = ge < NE;
    const int geC = valid ? ge : NE - 1;
    // residual re-read: cacheable (L2/L3-hot from the GEMM phase reads)
    const f32v4 r0 = *(const f32v4*)(edges + (size_t)geC * H + tc);
    const f32v4 r1 = *(const f32v4*)(edges + (size_t)geC * H + tc + 4);
    const float rr[8] = {r0.x, r0.y, r0.z, r0.w, r1.x, r1.y, r1.z, r1.w};
    float t8[8];
#pragma unroll
    for (int i = 0; i < 8; ++i) {
      const float n = acc[j][i] + bb[i];
      acc[j][i] = n;  // keep pre-residual value for the atomic pass
      t8[i] = n + rr[i];
    }
    float s1 = 0.f, s2 = 0.f;
#pragma unroll
    for (int i = 0; i < 8; ++i) { s1 += t8[i]; s2 = fmaf(t8[i], t8[i], s2); }
    // row held by the 8 lanes sharing te: xor 1,2,4
    s1 += __shfl_xor(s1, 1, 64); s2 += __shfl_xor(s2, 1, 64);
    s1 += __shfl_xor(s1, 2, 64); s2 += __shfl_xor(s2, 2, 64);
    s1 += __shfl_xor(s1, 4, 64); s2 += __shfl_xor(s2, 4, 64);
    const float mean = s1 * (1.0f / 64.0f);
    const float var = s2 * (1.0f / 64.0f) - mean * mean;
    const float rstd = rsqrtf(var + EPS);
    if (valid) {
      f32v4 o0, o1;
      o0.x = (t8[0] - mean) * rstd * ss[0] + ll[0];
      o0.y = (t8[1] - mean) * rstd * ss[1] + ll[1];
      o0.z = (t8[2] - mean) * rstd * ss[2] + ll[2];
      o0.w = (t8[3] - mean) * rstd * ss[3] + ll[3];
      o1.x = (t8[4] - mean) * rstd * ss[4] + ll[4];
      o1.y = (t8[5] - mean) * rstd * ss[5] + ll[5];
      o1.z = (t8[6] - mean) * rstd * ss[6] + ll[6];
      o1.w = (t8[7] - mean) * rstd * ss[7] + ll[7];
      float* po = edges_out + (size_t)ge * H + tc;
      __builtin_nontemporal_store(o0, (f32v4*)(po + 0));  // never re-read
      __builtin_nontemporal_store(o1, (f32v4*)(po + 4));
    }
  }

  // ---- epilogue part 2: per-wave transpose -> row-contiguous atomics ----
  // Wave wv owns block rows [64wv,64wv+64) + a private 4KB slice of aT: no
  // cross-wave hazard, no barriers. One atomic instr per edge covers the
  // full 256B recv row (8 sectors, 1x amplification) -- the r12 win.
  const int wv = tid >> 6;
  const int l = tid & 63;
  float* slice = aT + wv * 1024;  // 16 rows x 64 cols
#pragma unroll 1
  for (int s = 0; s < 4; ++s) {
    if ((l >> 4) == s) {
      const int rb = ((l >> 3) & 1) * 8;  // slice-row base for this lane
#pragma unroll
      for (int j = 0; j < 8; ++j) {
        f32v4 x0, x1;
        x0.x = acc[j][0]; x0.y = acc[j][1]; x0.z = acc[j][2]; x0.w = acc[j][3];
        x1.x = acc[j][4]; x1.y = acc[j][5]; x1.z = acc[j][6]; x1.w = acc[j][7];
        *(f32v4*)(&slice[(rb + j) * 64 + tc + 0]) = x0;
        *(f32v4*)(&slice[(rb + j) * 64 + tc + 4]) = x1;
      }
    }
#pragma unroll 4
    for (int e = 0; e < 16; ++e) {
      const int row = wv * 64 + s * 16 + e;
      const int ge = e0 + row;
      if (ge < NE) {  // uniform per instruction
        const float v = slice[e * 64 + l];  // stride-1 across lanes: free
        atomicAdd(recv_agg + (size_t)rBlk[row] * H + l, v);
      }
    }
  }
}

// ---- node kernel: unchanged (not the bottleneck, ~37 µs).
__global__ __launch_bounds__(256, 3) void node_tiled(
    const float* __restrict__ nodes, const float* recv_agg,
    const float* __restrict__ Wn, const float* __restrict__ bn,
    const float* __restrict__ ln_s, const float* __restrict__ ln_b,
    float* nodes_out) {
  __shared__ __align__(16) float aT[64 * 64];    // 16 KB: [k-k0][n]
  __shared__ __align__(16) float Wb[128 * 64];   // 32 KB
  const int tid = threadIdx.x;
  const int n0 = blockIdx.x * 64;

#pragma unroll
  for (int t = 0; t < 8; ++t) {
    int ci = t * 256 + tid;
    *(float4*)(&Wb[ci * 4]) = *(const float4*)(Wn + ci * 4);
  }

  float acc[4][4];
#pragma unroll
  for (int j = 0; j < 4; ++j)
#pragma unroll
    for (int i = 0; i < 4; ++i) acc[j][i] = 0.0f;

  const int te = (tid >> 4) * 4;
  const int tc = (tid & 15) * 4;

#pragma unroll
  for (int p = 0; p < 2; ++p) {
    const int k0 = 64 * p;
#pragma unroll
    for (int t = 0; t < 4; ++t) {
      int ci = t * 256 + tid;                     // 1024 float4
      int n = ci & 63, kq = ci >> 6;              // kq 0..15
      int kg = k0 + kq * 4;
      int gn = n0 + n;
      int gnc = gn < NN ? gn : NN - 1;
      const float* src = (kg < 64) ? (nodes + (size_t)gnc * H + kg)
                                   : (recv_agg + (size_t)gnc * H + (kg - 64));
      float4 v = *(const float4*)src;
      aT[(kq * 4 + 0) * 64 + n] = v.x;
      aT[(kq * 4 + 1) * 64 + n] = v.y;
      aT[(kq * 4 + 2) * 64 + n] = v.z;
      aT[(kq * 4 + 3) * 64 + n] = v.w;
    }
    __syncthreads();
#pragma unroll 4
    for (int kk = 0; kk < 64; ++kk) {
      float4 a4 = *(const float4*)(&aT[kk * 64 + te]);
      float4 w4 = *(const float4*)(&Wb[(k0 + kk) * 64 + tc]);
      float av[4] = {a4.x, a4.y, a4.z, a4.w};
      float wv[4] = {w4.x, w4.y, w4.z, w4.w};
#pragma unroll
      for (int j = 0; j < 4; ++j)
#pragma unroll
        for (int i = 0; i < 4; ++i) acc[j][i] += av[j] * wv[i];
    }
    __syncthreads();
  }

  const float4 bev = *(const float4*)(bn + tc);
  const float4 sev = *(const float4*)(ln_s + tc);
  const float4 biv = *(const float4*)(ln_b + tc);
#pragma unroll
  for (int j = 0; j < 4; ++j) {
    int gn = n0 + te + j;
    bool valid = gn < NN;
    float4 nv;
    if (valid) nv = *(const float4*)(nodes + (size_t)gn * H + tc);
    else { nv.x = nv.y = nv.z = nv.w = 0.0f; }
    float t0 = acc[j][0] + bev.x + nv.x;
    float t1 = acc[j][1] + bev.y + nv.y;
    float t2 = acc[j][2] + bev.z + nv.z;
    float t3 = acc[j][3] + bev.w + nv.w;
    float s1 = t0 + t1 + t2 + t3;
    float s2 = t0 * t0 + t1 * t1 + t2 * t2 + t3 * t3;
    s1 += __shfl_xor(s1, 1, 64); s2 += __shfl_xor(s2, 1, 64);
    s1 += __shfl_xor(s1, 2, 64); s2 += __shfl_xor(s2, 2, 64);
    s1 += __shfl_xor(s1, 4, 64); s2 += __shfl_xor(s2, 4, 64);
    s1 += __shfl_xor(s1, 8, 64); s2 += __shfl_xor(s2, 8, 64);
    float mean = s1 * (1.0f / 64.0f);
    float var = s2 * (1.0f / 64.0f) - mean * mean;
    float rstd = rsqrtf(var + EPS);
    if (valid) {
      float4 o;
      o.x = (t0 - mean) * rstd * sev.x + biv.x;
      o.y = (t1 - mean) * rstd * sev.y + biv.y;
      o.z = (t2 - mean) * rstd * sev.z + biv.z;
      o.w = (t3 - mean) * rstd * sev.w + biv.w;
      *(float4*)(nodes_out + (size_t)gn * H + tc) = o;
    }
  }
}

extern "C" void kernel_launch(void* const* d_in, const int* in_sizes, int n_in,
                              void* d_out, int out_size, void* d_ws, size_t ws_size,
                              hipStream_t stream) {
  const float* nodes      = (const float*)d_in[0];
  const float* edges      = (const float*)d_in[1];
  const int*   senders    = (const int*)d_in[2];
  const int*   receivers  = (const int*)d_in[3];
  const float* We         = (const float*)d_in[4];
  const float* be         = (const float*)d_in[5];
  const float* Wn         = (const float*)d_in[6];
  const float* bn         = (const float*)d_in[7];
  const float* ln_n_scale = (const float*)d_in[8];
  const float* ln_n_bias  = (const float*)d_in[9];
  const float* ln_e_scale = (const float*)d_in[10];
  const float* ln_e_bias  = (const float*)d_in[11];

  float* out = (float*)d_out;
  float* nodes_out = out;                       // [NN,64]; doubles as recv_agg
  float* edges_out = out + (size_t)NN * H;      // [NE,64]

  (void)hipMemsetAsync(nodes_out, 0, (size_t)NN * H * sizeof(float), stream);
  edge_p<<<(NE + 255) / 256, 256, 0, stream>>>(
      nodes, edges, senders, receivers, We, be, ln_e_scale, ln_e_bias,
      nodes_out, edges_out);
  node_tiled<<<(NN + 63) / 64, 256, 0, stream>>>(nodes, nodes_out, Wn, bn,
                                                 ln_n_scale, ln_n_bias, nodes_out);
}

// Round 12
// 447.130 us; speedup vs baseline: 4.1500x; 1.0166x over previous
//
#include <hip/hip_runtime.h>

#define H 64
#define NN 100000
#define NE 1000000
#define EPS 1e-6f

// ROUND 18: single-wave workgroups, ZERO barriers. r14/r15/r17 all plateau
// at 398-414us with occupancy pinned ~40% (~4 blocks/CU) regardless of LDS
// (21.5-41KB): block co-residency, not LDS, is the cap, and 24 full-drain
// __syncthreads per 4-wave block is the shared structure. Fix: block = 64
// edges = ONE wave, private 4KB aT + 4KB Wb, no __syncthreads anywhere
// (intra-wave LDS write->read is ordered by the in-order per-wave DS pipe +
// compiler lgkmcnt). Same 8x8 tile, same 64B A granule (r16 rule), W staged
// per phase as 4 dense 1KB copies (16B/lane stride = bank-clean), same
// row-contiguous atomic epilogue (r12 sector win), same cache policy (r14).
// VGPR ~110 -> 4 waves/SIMD = 16 waves/CU, now free-running instead of
// barrier-locked. __launch_bounds__(64,4): allocator cap 128, no spill.

typedef __attribute__((ext_vector_type(4))) float f32v4;

__global__ __launch_bounds__(64, 4) void edge_w1(
    const float* __restrict__ nodes, const float* __restrict__ edges,
    const int* __restrict__ senders, const int* __restrict__ receivers,
    const float* __restrict__ We, const float* __restrict__ be,
    const float* __restrict__ ln_s, const float* __restrict__ ln_b,
    float* recv_agg, float* __restrict__ edges_out) {
  __shared__ __align__(16) float aT[16 * 64];  // 4 KB: [k][edge], 1 phase
  __shared__ __align__(16) float Wb[16 * 64];  // 4 KB: current W chunk
  __shared__ int rIdx[64];                     // 256 B
  const int tid = threadIdx.x;                 // one wave
  const int e0 = blockIdx.x * 64;              // NE % 64 == 0: grid exact
  const int e = e0 + tid;
  const int sI = senders[e];
  const int rI = receivers[e];
  rIdx[tid] = rI;

  float acc[8][8];
#pragma unroll
  for (int j = 0; j < 8; ++j)
#pragma unroll
    for (int i = 0; i < 8; ++i) acc[j][i] = 0.0f;

  const int te = (tid >> 3) * 8;  // 8 groups x 8 edges (all in this wave)
  const int tc = (tid & 7) * 8;   // 8 groups x 8 cols

  // A for phase p: one full 64B line of this thread's own row
  // (p<4 edges, p<8 sender, else receiver; cacheable).
#define LOAD_A(P)                                                              \
  {                                                                            \
    const int p_ = (P);                                                        \
    const float* s_;                                                           \
    if (p_ < 4)      s_ = edges + (size_t)e * H + p_ * 16;                     \
    else if (p_ < 8) s_ = nodes + (size_t)sI * H + (p_ - 4) * 16;              \
    else             s_ = nodes + (size_t)rI * H + (p_ - 8) * 16;              \
    v0 = *(const f32v4*)(s_ + 0);  v1 = *(const f32v4*)(s_ + 4);               \
    v2 = *(const f32v4*)(s_ + 8);  v3 = *(const f32v4*)(s_ + 12);              \
  }

  f32v4 v0, v1, v2, v3;
  LOAD_A(0);

#pragma unroll 1
  for (int p = 0; p < 12; ++p) {
    // W chunk rows [16p,16p+16): 4 dense 1KB copies, 16B/lane stride
    // (bank-clean b128s); We is linear + L2-resident across all blocks.
    const float* wsrc = We + (size_t)p * (16 * 64);
    f32v4 w0 = *(const f32v4*)(wsrc + 0 * 256 + tid * 4);
    f32v4 w1 = *(const f32v4*)(wsrc + 1 * 256 + tid * 4);
    f32v4 w2 = *(const f32v4*)(wsrc + 2 * 256 + tid * 4);
    f32v4 w3 = *(const f32v4*)(wsrc + 3 * 256 + tid * 4);
    // A transpose write: aT[k][e=tid]; bank = tid%32: conflict-free.
    // In-order per-wave DS pipe: prior phase's reads complete first.
    aT[0 * 64 + tid] = v0.x;  aT[1 * 64 + tid] = v0.y;
    aT[2 * 64 + tid] = v0.z;  aT[3 * 64 + tid] = v0.w;
    aT[4 * 64 + tid] = v1.x;  aT[5 * 64 + tid] = v1.y;
    aT[6 * 64 + tid] = v1.z;  aT[7 * 64 + tid] = v1.w;
    aT[8 * 64 + tid] = v2.x;  aT[9 * 64 + tid] = v2.y;
    aT[10 * 64 + tid] = v2.z; aT[11 * 64 + tid] = v2.w;
    aT[12 * 64 + tid] = v3.x; aT[13 * 64 + tid] = v3.y;
    aT[14 * 64 + tid] = v3.z; aT[15 * 64 + tid] = v3.w;
    *(f32v4*)(&Wb[0 * 256 + tid * 4]) = w0;
    *(f32v4*)(&Wb[1 * 256 + tid * 4]) = w1;
    *(f32v4*)(&Wb[2 * 256 + tid * 4]) = w2;
    *(f32v4*)(&Wb[3 * 256 + tid * 4]) = w3;
    if (p < 11) LOAD_A(p + 1);  // gathers fly over this phase's compute
#pragma unroll 4
    for (int kk = 0; kk < 16; ++kk) {
      f32v4 a0 = *(const f32v4*)(&aT[kk * 64 + te + 0]);
      f32v4 a1 = *(const f32v4*)(&aT[kk * 64 + te + 4]);
      f32v4 q0 = *(const f32v4*)(&Wb[kk * 64 + tc + 0]);
      f32v4 q1 = *(const f32v4*)(&Wb[kk * 64 + tc + 4]);
      const float av[8] = {a0.x, a0.y, a0.z, a0.w, a1.x, a1.y, a1.z, a1.w};
      const float wv[8] = {q0.x, q0.y, q0.z, q0.w, q1.x, q1.y, q1.z, q1.w};
#pragma unroll
      for (int j = 0; j < 8; ++j)
#pragma unroll
        for (int i = 0; i < 8; ++i)
          acc[j][i] = fmaf(av[j], wv[i], acc[j][i]);
    }
  }
#undef LOAD_A

  // ---- epilogue part 1: bias -> LN -> store; acc := n (pre-residual) ----
  const f32v4 be0 = *(const f32v4*)(be + tc);
  const f32v4 be1 = *(const f32v4*)(be + tc + 4);
  const f32v4 se0 = *(const f32v4*)(ln_s + tc);
  const f32v4 se1 = *(const f32v4*)(ln_s + tc + 4);
  const f32v4 bi0 = *(const f32v4*)(ln_b + tc);
  const f32v4 bi1 = *(const f32v4*)(ln_b + tc + 4);
  const float bb[8] = {be0.x, be0.y, be0.z, be0.w, be1.x, be1.y, be1.z, be1.w};
  const float ss[8] = {se0.x, se0.y, se0.z, se0.w, se1.x, se1.y, se1.z, se1.w};
  const float ll[8] = {bi0.x, bi0.y, bi0.z, bi0.w, bi1.x, bi1.y, bi1.z, bi1.w};

#pragma unroll
  for (int j = 0; j < 8; ++j) {
    const int ge = e0 + te + j;  // always < NE (grid exact)
    // residual re-read: cacheable (L2/L3-hot from the GEMM phase reads)
    const f32v4 r0 = *(const f32v4*)(edges + (size_t)ge * H + tc);
    const f32v4 r1 = *(const f32v4*)(edges + (size_t)ge * H + tc + 4);
    const float rr[8] = {r0.x, r0.y, r0.z, r0.w, r1.x, r1.y, r1.z, r1.w};
    float t8[8];
#pragma unroll
    for (int i = 0; i < 8; ++i) {
      const float n = acc[j][i] + bb[i];
      acc[j][i] = n;  // keep pre-residual value for the atomic pass
      t8[i] = n + rr[i];
    }
    float s1 = 0.f, s2 = 0.f;
#pragma unroll
    for (int i = 0; i < 8; ++i) { s1 += t8[i]; s2 = fmaf(t8[i], t8[i], s2); }
    // row held by the 8 lanes sharing te: xor 1,2,4
    s1 += __shfl_xor(s1, 1, 64); s2 += __shfl_xor(s2, 1, 64);
    s1 += __shfl_xor(s1, 2, 64); s2 += __shfl_xor(s2, 2, 64);
    s1 += __shfl_xor(s1, 4, 64); s2 += __shfl_xor(s2, 4, 64);
    const float mean = s1 * (1.0f / 64.0f);
    const float var = s2 * (1.0f / 64.0f) - mean * mean;
    const float rstd = rsqrtf(var + EPS);
    f32v4 o0, o1;
    o0.x = (t8[0] - mean) * rstd * ss[0] + ll[0];
    o0.y = (t8[1] - mean) * rstd * ss[1] + ll[1];
    o0.z = (t8[2] - mean) * rstd * ss[2] + ll[2];
    o0.w = (t8[3] - mean) * rstd * ss[3] + ll[3];
    o1.x = (t8[4] - mean) * rstd * ss[4] + ll[4];
    o1.y = (t8[5] - mean) * rstd * ss[5] + ll[5];
    o1.z = (t8[6] - mean) * rstd * ss[6] + ll[6];
    o1.w = (t8[7] - mean) * rstd * ss[7] + ll[7];
    float* po = edges_out + (size_t)ge * H + tc;
    __builtin_nontemporal_store(o0, (f32v4*)(po + 0));  // never re-read
    __builtin_nontemporal_store(o1, (f32v4*)(po + 4));
  }

  // ---- epilogue part 2: in-wave transpose -> row-contiguous atomics ----
  // aT (4KB = 16 rows x 64 cols) reused as this wave's slice; intra-wave
  // DS ordering makes write->read safe without barriers (as before). One
  // atomic instr per edge covers the full 256B recv row (8 sectors, 1x
  // amplification) -- the r12 win.
#pragma unroll 1
  for (int s = 0; s < 4; ++s) {
    if ((tid >> 4) == s) {                 // 16 lanes own these 16 rows
      const int rb = ((tid >> 3) & 1) * 8; // slice-row base for this lane
#pragma unroll
      for (int j = 0; j < 8; ++j) {
        f32v4 x0, x1;
        x0.x = acc[j][0]; x0.y = acc[j][1]; x0.z = acc[j][2]; x0.w = acc[j][3];
        x1.x = acc[j][4]; x1.y = acc[j][5]; x1.z = acc[j][6]; x1.w = acc[j][7];
        *(f32v4*)(&aT[(rb + j) * 64 + tc + 0]) = x0;
        *(f32v4*)(&aT[(rb + j) * 64 + tc + 4]) = x1;
      }
    }
#pragma unroll 4
    for (int e2 = 0; e2 < 16; ++e2) {
      const int row = s * 16 + e2;
      const float v = aT[e2 * 64 + tid];  // stride-1 across lanes: free
      atomicAdd(recv_agg + (size_t)rIdx[row] * H + tid, v);
    }
  }
}

// ---- node kernel: unchanged (not the bottleneck, ~37 µs).
__global__ __launch_bounds__(256, 3) void node_tiled(
    const float* __restrict__ nodes, const float* recv_agg,
    const float* __restrict__ Wn, const float* __restrict__ bn,
    const float* __restrict__ ln_s, const float* __restrict__ ln_b,
    float* nodes_out) {
  __shared__ __align__(16) float aT[64 * 64];    // 16 KB: [k-k0][n]
  __shared__ __align__(16) float Wb[128 * 64];   // 32 KB
  const int tid = threadIdx.x;
  const int n0 = blockIdx.x * 64;

#pragma unroll
  for (int t = 0; t < 8; ++t) {
    int ci = t * 256 + tid;
    *(float4*)(&Wb[ci * 4]) = *(const float4*)(Wn + ci * 4);
  }

  float acc[4][4];
#pragma unroll
  for (int j = 0; j < 4; ++j)
#pragma unroll
    for (int i = 0; i < 4; ++i) acc[j][i] = 0.0f;

  const int te = (tid >> 4) * 4;
  const int tc = (tid & 15) * 4;

#pragma unroll
  for (int p = 0; p < 2; ++p) {
    const int k0 = 64 * p;
#pragma unroll
    for (int t = 0; t < 4; ++t) {
      int ci = t * 256 + tid;                     // 1024 float4
      int n = ci & 63, kq = ci >> 6;              // kq 0..15
      int kg = k0 + kq * 4;
      int gn = n0 + n;
      int gnc = gn < NN ? gn : NN - 1;
      const float* src = (kg < 64) ? (nodes + (size_t)gnc * H + kg)
                                   : (recv_agg + (size_t)gnc * H + (kg - 64));
      float4 v = *(const float4*)src;
      aT[(kq * 4 + 0) * 64 + n] = v.x;
      aT[(kq * 4 + 1) * 64 + n] = v.y;
      aT[(kq * 4 + 2) * 64 + n] = v.z;
      aT[(kq * 4 + 3) * 64 + n] = v.w;
    }
    __syncthreads();
#pragma unroll 4
    for (int kk = 0; kk < 64; ++kk) {
      float4 a4 = *(const float4*)(&aT[kk * 64 + te]);
      float4 w4 = *(const float4*)(&Wb[(k0 + kk) * 64 + tc]);
      float av[4] = {a4.x, a4.y, a4.z, a4.w};
      float wv[4] = {w4.x, w4.y, w4.z, w4.w};
#pragma unroll
      for (int j = 0; j < 4; ++j)
#pragma unroll
        for (int i = 0; i < 4; ++i) acc[j][i] += av[j] * wv[i];
    }
    __syncthreads();
  }

  const float4 bev = *(const float4*)(bn + tc);
  const float4 sev = *(const float4*)(ln_s + tc);
  const float4 biv = *(const float4*)(ln_b + tc);
#pragma unroll
  for (int j = 0; j < 4; ++j) {
    int gn = n0 + te + j;
    bool valid = gn < NN;
    float4 nv;
    if (valid) nv = *(const float4*)(nodes + (size_t)gn * H + tc);
    else { nv.x = nv.y = nv.z = nv.w = 0.0f; }
    float t0 = acc[j][0] + bev.x + nv.x;
    float t1 = acc[j][1] + bev.y + nv.y;
    float t2 = acc[j][2] + bev.z + nv.z;
    float t3 = acc[j][3] + bev.w + nv.w;
    float s1 = t0 + t1 + t2 + t3;
    float s2 = t0 * t0 + t1 * t1 + t2 * t2 + t3 * t3;
    s1 += __shfl_xor(s1, 1, 64); s2 += __shfl_xor(s2, 1, 64);
    s1 += __shfl_xor(s1, 2, 64); s2 += __shfl_xor(s2, 2, 64);
    s1 += __shfl_xor(s1, 4, 64); s2 += __shfl_xor(s2, 4, 64);
    s1 += __shfl_xor(s1, 8, 64); s2 += __shfl_xor(s2, 8, 64);
    float mean = s1 * (1.0f / 64.0f);
    float var = s2 * (1.0f / 64.0f) - mean * mean;
    float rstd = rsqrtf(var + EPS);
    if (valid) {
      float4 o;
      o.x = (t0 - mean) * rstd * sev.x + biv.x;
      o.y = (t1 - mean) * rstd * sev.y + biv.y;
      o.z = (t2 - mean) * rstd * sev.z + biv.z;
      o.w = (t3 - mean) * rstd * sev.w + biv.w;
      *(float4*)(nodes_out + (size_t)gn * H + tc) = o;
    }
  }
}

extern "C" void kernel_launch(void* const* d_in, const int* in_sizes, int n_in,
                              void* d_out, int out_size, void* d_ws, size_t ws_size,
                              hipStream_t stream) {
  const float* nodes      = (const float*)d_in[0];
  const float* edges      = (const float*)d_in[1];
  const int*   senders    = (const int*)d_in[2];
  const int*   receivers  = (const int*)d_in[3];
  const float* We         = (const float*)d_in[4];
  const float* be         = (const float*)d_in[5];
  const float* Wn         = (const float*)d_in[6];
  const float* bn         = (const float*)d_in[7];
  const float* ln_n_scale = (const float*)d_in[8];
  const float* ln_n_bias  = (const float*)d_in[9];
  const float* ln_e_scale = (const float*)d_in[10];
  const float* ln_e_bias  = (const float*)d_in[11];

  float* out = (float*)d_out;
  float* nodes_out = out;                       // [NN,64]; doubles as recv_agg
  float* edges_out = out + (size_t)NN * H;      // [NE,64]

  (void)hipMemsetAsync(nodes_out, 0, (size_t)NN * H * sizeof(float), stream);
  edge_w1<<<NE / 64, 64, 0, stream>>>(
      nodes, edges, senders, receivers, We, be, ln_e_scale, ln_e_bias,
      nodes_out, edges_out);
  node_tiled<<<(NN + 63) / 64, 256, 0, stream>>>(nodes, nodes_out, Wn, bn,
                                                 ln_n_scale, ln_n_bias, nodes_out);
}

// Round 13
// 284.179 us; speedup vs baseline: 6.5297x; 1.5734x over previous
//
#include <hip/hip_runtime.h>

#define H 64
#define NN 100000
#define NE 1000000
#define EPS 1e-6f

// ROUND 19: MFMA f16 edge GEMM. r18 proved the fp32 8x8 tile's LDS wall:
// 4x b128/64FMA/lane -> 4 waves demand 192cy LDS per 128cy SIMD -> VALU
// caps at measured 56%; 3 different schedules all ~396us. Fix: move the
// GEMM to the matrix pipe. mfma_f32_16x16x32_f16: A direct global->VGPR
// (32B/lane, 4 lanes/row = 128B per instr pair: no r16 amplification),
// W f16 in LDS [col][k] (400B padded stride = bank-floor b128 frags),
// staged once per block (one barrier total). 4 waves x 16 edges, 24 mfma
// per wave, fp32 accum. f16 input rounding: est max err ~5e-3 < 0.0156.
// D layout (m89): col=lane&15, row=(lane>>4)*4+reg -> LN via 4-level
// shfl_xor in 16-lane quadrants. Epilogue keeps r12's row-contiguous
// atomic (slice transpose) + r14 cache policy + NT stores (now coalesced
// 256B dword rows via slice).

typedef __attribute__((ext_vector_type(4))) float f32v4;
typedef __attribute__((ext_vector_type(4))) float floatx4;
typedef _Float16 half8 __attribute__((ext_vector_type(8)));
typedef _Float16 half4 __attribute__((ext_vector_type(4)));

__global__ __launch_bounds__(256, 3) void edge_mfma(
    const float* __restrict__ nodes, const float* __restrict__ edges,
    const int* __restrict__ senders, const int* __restrict__ receivers,
    const float* __restrict__ We, const float* __restrict__ be,
    const float* __restrict__ ln_s, const float* __restrict__ ln_b,
    float* recv_agg, float* __restrict__ edges_out) {
  __shared__ _Float16 Wl[64][200];              // 25.6 KB: W^T f16, [col][k],
                                                // 400B row stride (pad 8)
  __shared__ __align__(16) float slice[4][1024]; // 16 KB: per-wave 16x64
  const int tid = threadIdx.x;
  const int e0 = blockIdx.x * 64;               // NE % 64 == 0: grid exact

  // ---- W stage (once): thread t -> col = t&63, k-seg = (t>>6)*48.
  // Reads coalesced (64 consecutive dwords of row k per instr); writes
  // k-contiguous f16x4 (b64) per col.
  {
    const int col = tid & 63;
    const int ks = (tid >> 6) * 48;
#pragma unroll 4
    for (int m = 0; m < 12; ++m) {
      const int k4 = ks + m * 4;
      half4 hv;
      hv.x = (_Float16)We[(k4 + 0) * 64 + col];
      hv.y = (_Float16)We[(k4 + 1) * 64 + col];
      hv.z = (_Float16)We[(k4 + 2) * 64 + col];
      hv.w = (_Float16)We[(k4 + 3) * 64 + col];
      *(half4*)&Wl[col][k4] = hv;
    }
  }

  const int w = tid >> 6;    // wave 0..3: edges [e0+16w, e0+16w+16)
  const int l = tid & 63;
  const int q = l >> 4;      // 0..3: k-subblock / D row-quad
  const int r15 = l & 15;    // A row (edge) for frags; D col
  const int geR = e0 + w * 16 + r15;
  const int sI = senders[geR];
  const int rI = receivers[geR];
  const float* rowp[3] = {edges + (size_t)geR * H, nodes + (size_t)sI * H,
                          nodes + (size_t)rI * H};

  __syncthreads();  // W ready; the ONLY barrier. Waves free-run after.

  floatx4 acc[4];
#pragma unroll
  for (int ct = 0; ct < 4; ++ct) acc[ct] = (floatx4){0.f, 0.f, 0.f, 0.f};

  // 6 k-chunks of 32. A frag: lane reads 8 consecutive f32 of its edge row
  // (row = r15, k = kc*32 + q*8) -> cvt f16. 4 lanes/row cover 128B within
  // one instr pair -> fully coalesced, no sub-line amplification.
#pragma unroll
  for (int kc = 0; kc < 6; ++kc) {
    const float* src = rowp[kc >> 1] + (kc & 1) * 32 + q * 8;
    const f32v4 x0 = *(const f32v4*)(src + 0);
    const f32v4 x1 = *(const f32v4*)(src + 4);
    half8 af;
    af[0] = (_Float16)x0.x; af[1] = (_Float16)x0.y;
    af[2] = (_Float16)x0.z; af[3] = (_Float16)x0.w;
    af[4] = (_Float16)x1.x; af[5] = (_Float16)x1.y;
    af[6] = (_Float16)x1.z; af[7] = (_Float16)x1.w;
    const int kb = kc * 32 + q * 8;
    // B frags: col = ct*16 + r15, k = kb..kb+8 (k-contiguous in Wl)
    const half8 b0 = *(const half8*)&Wl[0 + r15][kb];
    const half8 b1 = *(const half8*)&Wl[16 + r15][kb];
    const half8 b2 = *(const half8*)&Wl[32 + r15][kb];
    const half8 b3 = *(const half8*)&Wl[48 + r15][kb];
    acc[0] = __builtin_amdgcn_mfma_f32_16x16x32_f16(af, b0, acc[0], 0, 0, 0);
    acc[1] = __builtin_amdgcn_mfma_f32_16x16x32_f16(af, b1, acc[1], 0, 0, 0);
    acc[2] = __builtin_amdgcn_mfma_f32_16x16x32_f16(af, b2, acc[2], 0, 0, 0);
    acc[3] = __builtin_amdgcn_mfma_f32_16x16x32_f16(af, b3, acc[3], 0, 0, 0);
  }

  // ---- epilogue, frag layout: lane holds cols {ct*16+r15} of edges
  // E_i = q*4+i (i=0..3); acc[ct][i] = D[E_i][ct*16+r15].
  float bev[4], ssv[4], llv[4];
#pragma unroll
  for (int ct = 0; ct < 4; ++ct) {
    bev[ct] = be[ct * 16 + r15];
    ssv[ct] = ln_s[ct * 16 + r15];
    llv[ct] = ln_b[ct * 16 + r15];
  }
  float nv[4][4], tv[4][4];  // [ct][i]
  float s1[4] = {0.f, 0.f, 0.f, 0.f}, s2[4] = {0.f, 0.f, 0.f, 0.f};
#pragma unroll
  for (int i = 0; i < 4; ++i) {
    const int geE = e0 + w * 16 + q * 4 + i;
#pragma unroll
    for (int ct = 0; ct < 4; ++ct) {
      const float n = acc[ct][i] + bev[ct];
      // residual: 64B segment per row per instr, L2-hot from GEMM reads
      const float rr = edges[(size_t)geE * H + ct * 16 + r15];
      nv[ct][i] = n;
      const float t = n + rr;
      tv[ct][i] = t;
      s1[i] += t;
      s2[i] = fmaf(t, t, s2[i]);
    }
  }
  // per-edge LN sums: reduce across the 16 lanes of this quadrant
#pragma unroll
  for (int i = 0; i < 4; ++i) {
    s1[i] += __shfl_xor(s1[i], 1, 64); s2[i] += __shfl_xor(s2[i], 1, 64);
    s1[i] += __shfl_xor(s1[i], 2, 64); s2[i] += __shfl_xor(s2[i], 2, 64);
    s1[i] += __shfl_xor(s1[i], 4, 64); s2[i] += __shfl_xor(s2[i], 4, 64);
    s1[i] += __shfl_xor(s1[i], 8, 64); s2[i] += __shfl_xor(s2[i], 8, 64);
  }

  float* sl = &slice[w][0];  // private per wave: no barriers needed
  // n -> slice (transpose) -> one row-contiguous atomic instr per edge
  // (256B row, 8 sectors fully covered: the r12 1x-amplification win)
#pragma unroll
  for (int i = 0; i < 4; ++i)
#pragma unroll
    for (int ct = 0; ct < 4; ++ct)
      sl[(q * 4 + i) * 64 + ct * 16 + r15] = nv[ct][i];
#pragma unroll 4
  for (int e2 = 0; e2 < 16; ++e2) {
    const int rb = __shfl(rI, e2, 64);  // edge e2's receiver (lane e2)
    const float v = sl[e2 * 64 + l];    // stride-1: bank-clean
    atomicAdd(recv_agg + (size_t)rb * H + l, v);
  }
  // LN output -> slice -> coalesced NT dword stores (256B/instr)
#pragma unroll
  for (int i = 0; i < 4; ++i) {
    const float mean = s1[i] * (1.0f / 64.0f);
    const float var = s2[i] * (1.0f / 64.0f) - mean * mean;
    const float rstd = rsqrtf(var + EPS);
#pragma unroll
    for (int ct = 0; ct < 4; ++ct)
      sl[(q * 4 + i) * 64 + ct * 16 + r15] =
          (tv[ct][i] - mean) * rstd * ssv[ct] + llv[ct];
  }
#pragma unroll 4
  for (int e2 = 0; e2 < 16; ++e2) {
    const float v = sl[e2 * 64 + l];
    __builtin_nontemporal_store(
        v, edges_out + (size_t)(e0 + w * 16 + e2) * H + l);
  }
}

// ---- node kernel: unchanged (not the bottleneck, ~37 µs).
__global__ __launch_bounds__(256, 3) void node_tiled(
    const float* __restrict__ nodes, const float* recv_agg,
    const float* __restrict__ Wn, const float* __restrict__ bn,
    const float* __restrict__ ln_s, const float* __restrict__ ln_b,
    float* nodes_out) {
  __shared__ __align__(16) float aT[64 * 64];    // 16 KB: [k-k0][n]
  __shared__ __align__(16) float Wb[128 * 64];   // 32 KB
  const int tid = threadIdx.x;
  const int n0 = blockIdx.x * 64;

#pragma unroll
  for (int t = 0; t < 8; ++t) {
    int ci = t * 256 + tid;
    *(float4*)(&Wb[ci * 4]) = *(const float4*)(Wn + ci * 4);
  }

  float acc[4][4];
#pragma unroll
  for (int j = 0; j < 4; ++j)
#pragma unroll
    for (int i = 0; i < 4; ++i) acc[j][i] = 0.0f;

  const int te = (tid >> 4) * 4;
  const int tc = (tid & 15) * 4;

#pragma unroll
  for (int p = 0; p < 2; ++p) {
    const int k0 = 64 * p;
#pragma unroll
    for (int t = 0; t < 4; ++t) {
      int ci = t * 256 + tid;                     // 1024 float4
      int n = ci & 63, kq = ci >> 6;              // kq 0..15
      int kg = k0 + kq * 4;
      int gn = n0 + n;
      int gnc = gn < NN ? gn : NN - 1;
      const float* src = (kg < 64) ? (nodes + (size_t)gnc * H + kg)
                                   : (recv_agg + (size_t)gnc * H + (kg - 64));
      float4 v = *(const float4*)src;
      aT[(kq * 4 + 0) * 64 + n] = v.x;
      aT[(kq * 4 + 1) * 64 + n] = v.y;
      aT[(kq * 4 + 2) * 64 + n] = v.z;
      aT[(kq * 4 + 3) * 64 + n] = v.w;
    }
    __syncthreads();
#pragma unroll 4
    for (int kk = 0; kk < 64; ++kk) {
      float4 a4 = *(const float4*)(&aT[kk * 64 + te]);
      float4 w4 = *(const float4*)(&Wb[(k0 + kk) * 64 + tc]);
      float av[4] = {a4.x, a4.y, a4.z, a4.w};
      float wv[4] = {w4.x, w4.y, w4.z, w4.w};
#pragma unroll
      for (int j = 0; j < 4; ++j)
#pragma unroll
        for (int i = 0; i < 4; ++i) acc[j][i] += av[j] * wv[i];
    }
    __syncthreads();
  }

  const float4 bev = *(const float4*)(bn + tc);
  const float4 sev = *(const float4*)(ln_s + tc);
  const float4 biv = *(const float4*)(ln_b + tc);
#pragma unroll
  for (int j = 0; j < 4; ++j) {
    int gn = n0 + te + j;
    bool valid = gn < NN;
    float4 nv;
    if (valid) nv = *(const float4*)(nodes + (size_t)gn * H + tc);
    else { nv.x = nv.y = nv.z = nv.w = 0.0f; }
    float t0 = acc[j][0] + bev.x + nv.x;
    float t1 = acc[j][1] + bev.y + nv.y;
    float t2 = acc[j][2] + bev.z + nv.z;
    float t3 = acc[j][3] + bev.w + nv.w;
    float s1 = t0 + t1 + t2 + t3;
    float s2 = t0 * t0 + t1 * t1 + t2 * t2 + t3 * t3;
    s1 += __shfl_xor(s1, 1, 64); s2 += __shfl_xor(s2, 1, 64);
    s1 += __shfl_xor(s1, 2, 64); s2 += __shfl_xor(s2, 2, 64);
    s1 += __shfl_xor(s1, 4, 64); s2 += __shfl_xor(s2, 4, 64);
    s1 += __shfl_xor(s1, 8, 64); s2 += __shfl_xor(s2, 8, 64);
    float mean = s1 * (1.0f / 64.0f);
    float var = s2 * (1.0f / 64.0f) - mean * mean;
    float rstd = rsqrtf(var + EPS);
    if (valid) {
      float4 o;
      o.x = (t0 - mean) * rstd * sev.x + biv.x;
      o.y = (t1 - mean) * rstd * sev.y + biv.y;
      o.z = (t2 - mean) * rstd * sev.z + biv.z;
      o.w = (t3 - mean) * rstd * sev.w + biv.w;
      *(float4*)(nodes_out + (size_t)gn * H + tc) = o;
    }
  }
}

extern "C" void kernel_launch(void* const* d_in, const int* in_sizes, int n_in,
                              void* d_out, int out_size, void* d_ws, size_t ws_size,
                              hipStream_t stream) {
  const float* nodes      = (const float*)d_in[0];
  const float* edges      = (const float*)d_in[1];
  const int*   senders    = (const int*)d_in[2];
  const int*   receivers  = (const int*)d_in[3];
  const float* We         = (const float*)d_in[4];
  const float* be         = (const float*)d_in[5];
  const float* Wn         = (const float*)d_in[6];
  const float* bn         = (const float*)d_in[7];
  const float* ln_n_scale = (const float*)d_in[8];
  const float* ln_n_bias  = (const float*)d_in[9];
  const float* ln_e_scale = (const float*)d_in[10];
  const float* ln_e_bias  = (const float*)d_in[11];

  float* out = (float*)d_out;
  float* nodes_out = out;                       // [NN,64]; doubles as recv_agg
  float* edges_out = out + (size_t)NN * H;      // [NE,64]

  (void)hipMemsetAsync(nodes_out, 0, (size_t)NN * H * sizeof(float), stream);
  edge_mfma<<<NE / 64, 256, 0, stream>>>(
      nodes, edges, senders, receivers, We, be, ln_e_scale, ln_e_bias,
      nodes_out, edges_out);
  node_tiled<<<(NN + 63) / 64, 256, 0, stream>>>(nodes, nodes_out, Wn, bn,
                                                 ln_n_scale, ln_n_bias, nodes_out);
}